// Round 8
// baseline (346.782 us; speedup 1.0000x reference)
//
#include <hip/hip_runtime.h>
#include <hip/hip_cooperative_groups.h>

namespace cg = cooperative_groups;

typedef short short4v __attribute__((ext_vector_type(4)));
typedef short short8 __attribute__((ext_vector_type(8)));
typedef float floatx4 __attribute__((ext_vector_type(4)));
typedef unsigned int uint;
typedef unsigned short ushort;

#define CH 512
#define NN 2048
#define DD 128
#define RSCALE 0.08838834764831845f  // 1/sqrt(128)

__device__ __forceinline__ float bf2f(ushort u) {
    union { uint i; float f; } v; v.i = ((uint)u) << 16; return v.f;
}
__device__ __forceinline__ ushort f2bf(float f) {
    union { float f; uint u; } v; v.f = f;
    uint u = v.u;
    return (ushort)((u + 0x7fffu + ((u >> 16) & 1u)) >> 16);
}

// ---------------------------------------------------------------------------
// K0: weights -> bf16 AND zero lsum AND zero out (merged; one launch).
// ---------------------------------------------------------------------------
__global__ __launch_bounds__(256) void k0_prep(
    const float* __restrict__ wqk, const float* __restrict__ wv,
    ushort* __restrict__ Wbf, float* __restrict__ lsum,
    float* __restrict__ out)
{
    int gid = blockIdx.x * 256 + threadIdx.x;
    if (gid < 32768) {
        int base = gid * 4;
        const float* src = (base < 65536) ? (wqk + base) : (wv + base - 65536);
        float4 v = *(const float4*)src;
        short4v o;
        o[0] = (short)f2bf(v.x); o[1] = (short)f2bf(v.y);
        o[2] = (short)f2bf(v.z); o[3] = (short)f2bf(v.w);
        *(short4v*)&Wbf[base] = o;
    }
    if (gid < 16384) lsum[gid] = 0.0f;
    float4 z; z.x = 0.f; z.y = 0.f; z.z = 0.f; z.w = 0.f;
#pragma unroll
    for (int i = 0; i < 4; i++)
        *(float4*)&out[(size_t)(gid + i * 131072) * 4] = z;
}

// ---------------------------------------------------------------------------
// K1: projections, d-stack split across h; c-step 64 (8 iterations).
// Grid (64 nt, 2 h, 8 b) = 1024 blocks. LDS 33280 -> 4 blocks/CU.
// ---------------------------------------------------------------------------
__global__ __launch_bounds__(256) void k1_proj(
    const float* __restrict__ x,
    const ushort* __restrict__ Wbf,
    const float* __restrict__ bv,
    ushort* __restrict__ Q,
    ushort* __restrict__ VT)
{
    const int nt = blockIdx.x;   // 0..63
    const int h  = blockIdx.y;   // 0..1 (0: Q rows, 1: V rows)
    const int b  = blockIdx.z;   // 0..7
    const int n0 = nt * 32;
    const int t = threadIdx.x;
    const int lane = t & 63, w = t >> 6, l15 = lane & 15, quad = lane >> 4;

    __shared__ __attribute__((aligned(16))) ushort As[32 * 72];
    __shared__ __attribute__((aligned(16))) ushort Bs[128 * 72];
    __shared__ __attribute__((aligned(16))) ushort Vt[128 * 40];

    floatx4 acc[2][2];
#pragma unroll
    for (int i = 0; i < 2; i++)
#pragma unroll
        for (int j = 0; j < 2; j++) acc[i][j] = (floatx4)(0.0f);

    const float* xb = x + b * (CH * NN) + n0;
    const ushort* Wh = Wbf + h * 128 * CH;

    const int an = t & 31, ag = t >> 5;       // A-stage: n, c-chunk (0..7)

    for (int c0 = 0; c0 < CH; c0 += 64) {
        // stage A: [32 n][64 c], fp32 -> bf16, 8 elems/thread
        {
            short8 v;
#pragma unroll
            for (int i = 0; i < 8; i++)
                v[i] = (short)f2bf(xb[(c0 + ag * 8 + i) * NN + an]);
            *(short8*)&As[an * 72 + ag * 8] = v;
        }
        // stage B: [128 rows][64 c], 4 x b128/thread
#pragma unroll
        for (int rep = 0; rep < 4; rep++) {
            int idx = rep * 256 + t;
            int row = idx >> 3, g = idx & 7;
            *(short8*)&Bs[row * 72 + g * 8] = *(const short8*)&Wh[row * CH + c0 + g * 8];
        }
        __syncthreads();
#pragma unroll
        for (int kd = 0; kd < 2; kd++) {
            short8 a0 = *(short8*)&As[(l15) * 72 + kd * 32 + quad * 8];
            short8 a1 = *(short8*)&As[(16 + l15) * 72 + kd * 32 + quad * 8];
#pragma unroll
            for (int dt2 = 0; dt2 < 2; dt2++) {
                short8 bf = *(short8*)&Bs[(w * 32 + dt2 * 16 + l15) * 72 + kd * 32 + quad * 8];
                acc[0][dt2] = __builtin_amdgcn_mfma_f32_16x16x32_bf16(a0, bf, acc[0][dt2], 0, 0, 0);
                acc[1][dt2] = __builtin_amdgcn_mfma_f32_16x16x32_bf16(a1, bf, acc[1][dt2], 0, 0, 0);
            }
        }
        __syncthreads();
    }

    // epilogue
#pragma unroll
    for (int ns = 0; ns < 2; ns++)
#pragma unroll
        for (int dt2 = 0; dt2 < 2; dt2++) {
            int ds_ = w * 32 + dt2 * 16 + l15;  // 0..127
#pragma unroll
            for (int r = 0; r < 4; r++) {
                int nl = ns * 16 + quad * 4 + r;
                float val = acc[ns][dt2][r];
                if (h == 0) {
                    Q[b * (NN * DD) + (n0 + nl) * DD + ds_] = f2bf(val);
                } else {
                    Vt[ds_ * 40 + nl] = f2bf(val + bv[ds_]);
                }
            }
        }
    if (h == 1) {
        __syncthreads();
#pragma unroll
        for (int rep = 0; rep < 2; rep++) {
            int idx = rep * 256 + t;
            int dv = idx >> 2, seg = idx & 3;
            *(short8*)&VT[((size_t)b * DD + dv) * NN + n0 + seg * 8] =
                *(short8*)&Vt[dv * 40 + seg * 8];
        }
    }
}

// ---------------------------------------------------------------------------
// K_COOP: kl_sum + fused attention MERGED via grid-wide sync.
// Grid (64 mt, 2 h, 8 b) = 1024 blocks = EXACTLY 4/CU x 256 CU (co-resident).
// Pass 1: each block computes its S[32m x 1024n] tile, column-sums e^S over
// its 32 m-rows, atomicAdd into lsum[b][n]. grid.sync(). Pass 2: proven r3
// loop (S * 1/lsum[n] -> Ps -> PV), 2-contrib fp32 atomic out epilogue.
// lsum read with agent-scope coherent loads (per-XCD L2 not coherent in-kernel).
// LDS 40192 -> 4 blocks/CU. Fallback to separate kernels if coop launch fails.
// ---------------------------------------------------------------------------
__global__ __launch_bounds__(256, 4) void k_coop(
    const ushort* __restrict__ Q,   // [B][N][D] bf16
    const ushort* __restrict__ VT,  // [B][D][N] bf16 (unscaled, +bias)
    float* __restrict__ lsum,       // [B][N] (pre-zeroed)
    float* __restrict__ out)        // [B][D][N] fp32 (pre-zeroed)
{
    const int mt = blockIdx.x;  // 0..63
    const int h  = blockIdx.y;  // 0..1
    const int b  = blockIdx.z;
    const int m0 = mt * 32;
    const int t = threadIdx.x;
    const int lane = t & 63, w = t >> 6, l15 = lane & 15, quad = lane >> 4;

    __shared__ __attribute__((aligned(16))) ushort Qn[64 * 136];
    __shared__ __attribute__((aligned(16))) ushort Vs[128 * 72];
    __shared__ __attribute__((aligned(16))) ushort Ps[32 * 68];

    const ushort* Qb = Q + b * (NN * DD);
    const ushort* VTb = VT + (size_t)b * DD * NN;
    float* lb = lsum + b * NN;

    // stage Qm (32 rows x 128 d) through Qn rows 0..31, hoist to regs
#pragma unroll
    for (int rep = 0; rep < 2; rep++) {
        int idx = rep * 256 + t;
        int row = idx >> 4, g = idx & 15;
        *(short8*)&Qn[row * 136 + g * 8] = *(const short8*)&Qb[(m0 + row) * DD + g * 8];
    }
    __syncthreads();

    short8 qm[2][4];
#pragma unroll
    for (int ms = 0; ms < 2; ms++)
#pragma unroll
        for (int kd = 0; kd < 4; kd++)
            qm[ms][kd] = *(short8*)&Qn[(ms * 16 + l15) * 136 + kd * 32 + quad * 8];

    // per-thread staging coordinates
    const int qsr = t >> 4, qsg = t & 15;   // Qn: row sub, 16B chunk
    const int vsd = t >> 3, vsg = t & 7;    // Vs: d sub, 16B chunk

    short8 qr[4], vr[4];  // in-flight next tile (T14)

#define LOADQ(NC)                                                              \
    do {                                                                       \
        _Pragma("unroll")                                                      \
        for (int rep = 0; rep < 4; rep++)                                      \
            qr[rep] = *(const short8*)&Qb[((NC) + rep * 16 + qsr) * DD + qsg * 8]; \
    } while (0)
#define LOADV(NC)                                                              \
    do {                                                                       \
        _Pragma("unroll")                                                      \
        for (int rep = 0; rep < 4; rep++)                                      \
            vr[rep] = *(const short8*)&VTb[(size_t)(rep * 32 + vsd) * NN + (NC) + vsg * 8]; \
    } while (0)

    const int nbeg = h * (NN / 2), nend = nbeg + (NN / 2);

    // ===================== PASS 1: lsum column-sums ========================
    LOADQ(nbeg);
    for (int n0c = nbeg; n0c < nend; n0c += 64) {
        __syncthreads();  // prior reads of Qn complete
#pragma unroll
        for (int rep = 0; rep < 4; rep++)
            *(short8*)&Qn[(rep * 16 + qsr) * 136 + qsg * 8] = qr[rep];
        __syncthreads();
        if (n0c + 64 < nend) LOADQ(n0c + 64);

        short8 bq[4];
#pragma unroll
        for (int kd = 0; kd < 4; kd++)
            bq[kd] = *(short8*)&Qn[(w * 16 + l15) * 136 + kd * 32 + quad * 8];

        float colsum = 0.0f;
#pragma unroll
        for (int ms = 0; ms < 2; ms++) {
            floatx4 s = (floatx4)(0.0f);
#pragma unroll
            for (int kd = 0; kd < 4; kd++)
                s = __builtin_amdgcn_mfma_f32_16x16x32_bf16(qm[ms][kd], bq[kd], s, 0, 0, 0);
#pragma unroll
            for (int r = 0; r < 4; r++)
                colsum += __expf(s[r] * RSCALE);
        }
        // sum over the 4 quads (rows quad*4+r within each ms): full 32-m sum
        colsum += __shfl_xor(colsum, 16);
        colsum += __shfl_xor(colsum, 32);
        if (lane < 16)
            atomicAdd(&lb[n0c + w * 16 + lane], colsum);
    }

    // prefetch pass-2 first tile while syncing (const data, safe in flight)
    LOADQ(nbeg);
    LOADV(nbeg);
    __threadfence();
    cg::this_grid().sync();

    // ===================== PASS 2: normalized attention ====================
    floatx4 acc[2][2];
#pragma unroll
    for (int i = 0; i < 2; i++)
#pragma unroll
        for (int j = 0; j < 2; j++) acc[i][j] = (floatx4)(0.0f);

    for (int n0c = nbeg; n0c < nend; n0c += 64) {
        // coherent (agent-scope) read: lsum written by other XCDs' atomics
        float lw = __hip_atomic_load(&lb[n0c + w * 16 + l15],
                                     __ATOMIC_RELAXED, __HIP_MEMORY_SCOPE_AGENT);
        __syncthreads();  // prior iter's reads complete
#pragma unroll
        for (int rep = 0; rep < 4; rep++)
            *(short8*)&Qn[(rep * 16 + qsr) * 136 + qsg * 8] = qr[rep];
#pragma unroll
        for (int rep = 0; rep < 4; rep++)
            *(short8*)&Vs[(rep * 32 + vsd) * 72 + vsg * 8] = vr[rep];
        __syncthreads();  // tile visible

        if (n0c + 64 < nend) { LOADQ(n0c + 64); LOADV(n0c + 64); }

        // S stage: wave w owns n-band w*16; computes S[32 m][16 n]
        {
            float linv = 1.0f / lw;
            short8 bq[4];
#pragma unroll
            for (int kd = 0; kd < 4; kd++)
                bq[kd] = *(short8*)&Qn[(w * 16 + l15) * 136 + kd * 32 + quad * 8];
#pragma unroll
            for (int ms = 0; ms < 2; ms++) {
                floatx4 s = (floatx4)(0.0f);
#pragma unroll
                for (int kd = 0; kd < 4; kd++)
                    s = __builtin_amdgcn_mfma_f32_16x16x32_bf16(qm[ms][kd], bq[kd], s, 0, 0, 0);
#pragma unroll
                for (int r = 0; r < 4; r++) {
                    float p = __expf(s[r] * RSCALE) * linv;
                    Ps[(ms * 16 + quad * 4 + r) * 68 + w * 16 + l15] = f2bf(p);
                }
            }
        }
        __syncthreads();  // Ps ready

        // PV stage: wave w owns d-band w*32
#pragma unroll
        for (int kn = 0; kn < 2; kn++) {
            short8 va0 = *(short8*)&Vs[(w * 32 + l15) * 72 + kn * 32 + quad * 8];
            short8 va1 = *(short8*)&Vs[(w * 32 + 16 + l15) * 72 + kn * 32 + quad * 8];
#pragma unroll
            for (int mf = 0; mf < 2; mf++) {
                short8 pb = *(short8*)&Ps[(mf * 16 + l15) * 68 + kn * 32 + quad * 8];
                acc[0][mf] = __builtin_amdgcn_mfma_f32_16x16x32_bf16(va0, pb, acc[0][mf], 0, 0, 0);
                acc[1][mf] = __builtin_amdgcn_mfma_f32_16x16x32_bf16(va1, pb, acc[1][mf], 0, 0, 0);
            }
        }
    }
#undef LOADQ
#undef LOADV

    // epilogue: atomic accumulate into out (2 contributions/element total)
    float* ob = out + (size_t)b * DD * NN;
#pragma unroll
    for (int dsub = 0; dsub < 2; dsub++)
#pragma unroll
        for (int mf = 0; mf < 2; mf++)
#pragma unroll
            for (int r = 0; r < 4; r++) {
                int d = w * 32 + dsub * 16 + quad * 4 + r;
                atomicAdd(&ob[(size_t)d * NN + m0 + mf * 16 + l15], acc[dsub][mf][r]);
            }
}

// ---------------------------------------------------------------------------
// KL: l_n row sums (FALLBACK path if cooperative launch unavailable).
// Proven round-3 version (pad 72, k-split staging). LDS 36864 -> 4 blocks/CU.
// ---------------------------------------------------------------------------
__global__ __launch_bounds__(256, 4) void kl_sum(
    const ushort* __restrict__ Q,   // [B][N][D] bf16
    float* __restrict__ lsum)       // [B][N]
{
    int pid = blockIdx.x;  // 0..135
    const int b = blockIdx.y;
    int it = 0;
    while (pid >= (16 - it)) { pid -= (16 - it); it++; }
    const int jt = it + pid;
    const int i0 = it * 128, j0 = jt * 128;
    const int t = threadIdx.x;
    const int lane = t & 63, w = t >> 6, l15 = lane & 15, quad = lane >> 4;
    const int wi = (w >> 1) * 64, wj = (w & 1) * 64;

    __shared__ __attribute__((aligned(16))) ushort Qi[128 * 72];
    __shared__ __attribute__((aligned(16))) ushort Qj[128 * 72];

    const ushort* Qb = Q + b * (NN * DD);

    floatx4 acc[4][4];
#pragma unroll
    for (int i = 0; i < 4; i++)
#pragma unroll
        for (int j = 0; j < 4; j++) acc[i][j] = (floatx4)(0.0f);

    for (int kh = 0; kh < 2; kh++) {
        if (kh) __syncthreads();
#pragma unroll
        for (int rep = 0; rep < 4; rep++) {
            int idx = rep * 256 + t;
            int row = idx >> 3, g = idx & 7;
            *(short8*)&Qi[row * 72 + g * 8] = *(const short8*)&Qb[(i0 + row) * DD + kh * 64 + g * 8];
            *(short8*)&Qj[row * 72 + g * 8] = *(const short8*)&Qb[(j0 + row) * DD + kh * 64 + g * 8];
        }
        __syncthreads();

#pragma unroll
        for (int kd = 0; kd < 2; kd++) {
            short8 afr[4], bfr[4];
#pragma unroll
            for (int nt = 0; nt < 4; nt++)
                afr[nt] = *(short8*)&Qi[(wi + nt * 16 + l15) * 72 + kd * 32 + quad * 8];
#pragma unroll
            for (int mt = 0; mt < 4; mt++)
                bfr[mt] = *(short8*)&Qj[(wj + mt * 16 + l15) * 72 + kd * 32 + quad * 8];
#pragma unroll
            for (int nt = 0; nt < 4; nt++)
#pragma unroll
                for (int mt = 0; mt < 4; mt++)
                    acc[nt][mt] = __builtin_amdgcn_mfma_f32_16x16x32_bf16(afr[nt], bfr[mt], acc[nt][mt], 0, 0, 0);
        }
    }

    float cs[4] = {0.f, 0.f, 0.f, 0.f};
#pragma unroll
    for (int nt = 0; nt < 4; nt++) {
        float rs[4] = {0.f, 0.f, 0.f, 0.f};
#pragma unroll
        for (int mt = 0; mt < 4; mt++)
#pragma unroll
            for (int r = 0; r < 4; r++) {
                float p = __expf(acc[nt][mt][r] * RSCALE);
                rs[r] += p;
                cs[mt] += p;
            }
#pragma unroll
        for (int r = 0; r < 4; r++) {
            float s = rs[r];
            s += __shfl_xor(s, 1);
            s += __shfl_xor(s, 2);
            s += __shfl_xor(s, 4);
            s += __shfl_xor(s, 8);
            if (l15 == 0)
                atomicAdd(&lsum[b * NN + i0 + wi + nt * 16 + quad * 4 + r], s);
        }
    }
    if (it != jt) {
#pragma unroll
        for (int mt = 0; mt < 4; mt++) {
            float s = cs[mt];
            s += __shfl_xor(s, 16);
            s += __shfl_xor(s, 32);
            if (lane < 16)
                atomicAdd(&lsum[b * NN + j0 + wj + mt * 16 + l15], s);
        }
    }
}

// ---------------------------------------------------------------------------
// K3 (FALLBACK): round-3 proven fused attention, h=2, 2-contrib atomics.
// ---------------------------------------------------------------------------
__global__ __launch_bounds__(256, 4) void k_fused_sep(
    const ushort* __restrict__ Q,
    const ushort* __restrict__ VT,
    const float* __restrict__ lsum,
    float* __restrict__ out)
{
    const int mt = blockIdx.x;  // 0..63
    const int h  = blockIdx.y;  // 0..1
    const int b  = blockIdx.z;
    const int m0 = mt * 32;
    const int t = threadIdx.x;
    const int lane = t & 63, w = t >> 6, l15 = lane & 15, quad = lane >> 4;

    __shared__ __attribute__((aligned(16))) ushort Qn[64 * 136];
    __shared__ __attribute__((aligned(16))) ushort Vs[128 * 72];
    __shared__ __attribute__((aligned(16))) ushort Ps[32 * 68];

    const ushort* Qb = Q + b * (NN * DD);
    const ushort* VTb = VT + (size_t)b * DD * NN;
    const float* lb = lsum + b * NN;

#pragma unroll
    for (int rep = 0; rep < 2; rep++) {
        int idx = rep * 256 + t;
        int row = idx >> 4, g = idx & 15;
        *(short8*)&Qn[row * 136 + g * 8] = *(const short8*)&Qb[(m0 + row) * DD + g * 8];
    }
    __syncthreads();

    short8 qm[2][4];
#pragma unroll
    for (int ms = 0; ms < 2; ms++)
#pragma unroll
        for (int kd = 0; kd < 4; kd++)
            qm[ms][kd] = *(short8*)&Qn[(ms * 16 + l15) * 136 + kd * 32 + quad * 8];

    floatx4 acc[2][2];
#pragma unroll
    for (int i = 0; i < 2; i++)
#pragma unroll
        for (int j = 0; j < 2; j++) acc[i][j] = (floatx4)(0.0f);

    const int qsr = t >> 4, qsg = t & 15;
    const int vsd = t >> 3, vsg = t & 7;

    short8 qr[4], vr[4];

#define LOADR(NC)                                                              \
    do {                                                                       \
        _Pragma("unroll")                                                      \
        for (int rep = 0; rep < 4; rep++)                                      \
            qr[rep] = *(const short8*)&Qb[((NC) + rep * 16 + qsr) * DD + qsg * 8]; \
        _Pragma("unroll")                                                      \
        for (int rep = 0; rep < 4; rep++)                                      \
            vr[rep] = *(const short8*)&VTb[(size_t)(rep * 32 + vsd) * NN + (NC) + vsg * 8]; \
    } while (0)

    const int nbeg = h * (NN / 2), nend = nbeg + (NN / 2);

    LOADR(nbeg);

    for (int n0c = nbeg; n0c < nend; n0c += 64) {
        float lw = lb[n0c + w * 16 + l15];
        __syncthreads();
#pragma unroll
        for (int rep = 0; rep < 4; rep++)
            *(short8*)&Qn[(rep * 16 + qsr) * 136 + qsg * 8] = qr[rep];
#pragma unroll
        for (int rep = 0; rep < 4; rep++)
            *(short8*)&Vs[(rep * 32 + vsd) * 72 + vsg * 8] = vr[rep];
        __syncthreads();

        if (n0c + 64 < nend) LOADR(n0c + 64);

        {
            float linv = 1.0f / lw;
            short8 bq[4];
#pragma unroll
            for (int kd = 0; kd < 4; kd++)
                bq[kd] = *(short8*)&Qn[(w * 16 + l15) * 136 + kd * 32 + quad * 8];
#pragma unroll
            for (int ms = 0; ms < 2; ms++) {
                floatx4 s = (floatx4)(0.0f);
#pragma unroll
                for (int kd = 0; kd < 4; kd++)
                    s = __builtin_amdgcn_mfma_f32_16x16x32_bf16(qm[ms][kd], bq[kd], s, 0, 0, 0);
#pragma unroll
                for (int r = 0; r < 4; r++) {
                    float p = __expf(s[r] * RSCALE) * linv;
                    Ps[(ms * 16 + quad * 4 + r) * 68 + w * 16 + l15] = f2bf(p);
                }
            }
        }
        __syncthreads();

#pragma unroll
        for (int kn = 0; kn < 2; kn++) {
            short8 va0 = *(short8*)&Vs[(w * 32 + l15) * 72 + kn * 32 + quad * 8];
            short8 va1 = *(short8*)&Vs[(w * 32 + 16 + l15) * 72 + kn * 32 + quad * 8];
#pragma unroll
            for (int mf = 0; mf < 2; mf++) {
                short8 pb = *(short8*)&Ps[(mf * 16 + l15) * 68 + kn * 32 + quad * 8];
                acc[0][mf] = __builtin_amdgcn_mfma_f32_16x16x32_bf16(va0, pb, acc[0][mf], 0, 0, 0);
                acc[1][mf] = __builtin_amdgcn_mfma_f32_16x16x32_bf16(va1, pb, acc[1][mf], 0, 0, 0);
            }
        }
    }
#undef LOADR

    float* ob = out + (size_t)b * DD * NN;
#pragma unroll
    for (int dsub = 0; dsub < 2; dsub++)
#pragma unroll
        for (int mf = 0; mf < 2; mf++)
#pragma unroll
            for (int r = 0; r < 4; r++) {
                int d = w * 32 + dsub * 16 + quad * 4 + r;
                atomicAdd(&ob[(size_t)d * NN + m0 + mf * 16 + l15], acc[dsub][mf][r]);
            }
}

// ---------------------------------------------------------------------------
// Fallback path (small ws) — proven kernels
// ---------------------------------------------------------------------------
__global__ __launch_bounds__(256) void k1_fb(
    const float* __restrict__ x, const float* __restrict__ wqk,
    const float* __restrict__ wv, const float* __restrict__ bv,
    ushort* __restrict__ Q, ushort* __restrict__ V)
{
    const int nt = blockIdx.x;
    const int b  = blockIdx.y;
    const int n0 = nt * 32;
    const int t = threadIdx.x;
    const int lane = t & 63, w = t >> 6, l15 = lane & 15, quad = lane >> 4;

    __shared__ __attribute__((aligned(16))) ushort As[32 * 40];
    __shared__ __attribute__((aligned(16))) ushort Bs[256 * 40];

    floatx4 acc[2][4];
#pragma unroll
    for (int i = 0; i < 2; i++)
#pragma unroll
        for (int j = 0; j < 4; j++) acc[i][j] = (floatx4)(0.0f);

    const float* xb = x + b * (CH * NN) + n0;

    for (int c0 = 0; c0 < CH; c0 += 32) {
        {
            int n = t & 31, g = t >> 5;
            short4v v;
#pragma unroll
            for (int i = 0; i < 4; i++)
                v[i] = (short)f2bf(xb[(c0 + g * 4 + i) * NN + n]);
            *(short4v*)&As[n * 40 + g * 4] = v;
        }
#pragma unroll
        for (int rep = 0; rep < 16; rep++) {
            int idx = rep * 256 + t;
            int row = idx >> 4, cp = idx & 15;
            const float* wf = (row < 128) ? (wqk + row * CH) : (wv + (row - 128) * CH);
            uint pack = (uint)f2bf(wf[c0 + cp * 2]) | ((uint)f2bf(wf[c0 + cp * 2 + 1]) << 16);
            *(uint*)&Bs[row * 40 + cp * 2] = pack;
        }
        __syncthreads();
        short8 a0 = *(short8*)&As[(l15) * 40 + quad * 8];
        short8 a1 = *(short8*)&As[(16 + l15) * 40 + quad * 8];
#pragma unroll
        for (int dt2 = 0; dt2 < 4; dt2++) {
            short8 bf = *(short8*)&Bs[(w * 64 + dt2 * 16 + l15) * 40 + quad * 8];
            acc[0][dt2] = __builtin_amdgcn_mfma_f32_16x16x32_bf16(a0, bf, acc[0][dt2], 0, 0, 0);
            acc[1][dt2] = __builtin_amdgcn_mfma_f32_16x16x32_bf16(a1, bf, acc[1][dt2], 0, 0, 0);
        }
        __syncthreads();
    }
#pragma unroll
    for (int ns = 0; ns < 2; ns++)
#pragma unroll
        for (int dt2 = 0; dt2 < 4; dt2++) {
            int ds_ = w * 64 + dt2 * 16 + l15;
#pragma unroll
            for (int r = 0; r < 4; r++) {
                int n = n0 + ns * 16 + quad * 4 + r;
                float val = acc[ns][dt2][r];
                if (ds_ < 128) {
                    Q[b * (NN * DD) + n * DD + ds_] = f2bf(val);
                } else {
                    int dv = ds_ - 128;
                    V[b * (NN * DD) + n * DD + dv] = f2bf(val + bv[dv]);
                }
            }
        }
}

__global__ __launch_bounds__(256) void k2_norm(
    const ushort* __restrict__ Q, ushort* __restrict__ V)
{
    const int ntile = blockIdx.x;
    const int b = blockIdx.y;
    const int n0 = ntile * 64;
    const int t = threadIdx.x;
    const int lane = t & 63, w = t >> 6, l15 = lane & 15, quad = lane >> 4;

    __shared__ __attribute__((aligned(16))) ushort Qs[64 * 136];
    __shared__ __attribute__((aligned(16))) ushort Qm2[64 * 136];

    const ushort* Qb = Q + b * (NN * DD);

#pragma unroll
    for (int rep = 0; rep < 16; rep++) {
        int idx = rep * 256 + t;
        int row = idx >> 6, dp = idx & 63;
        *(uint*)&Qs[row * 136 + dp * 2] = *(const uint*)&Qb[(n0 + row) * DD + dp * 2];
    }
    __syncthreads();

    short8 afr[4];
#pragma unroll
    for (int kd = 0; kd < 4; kd++)
        afr[kd] = *(short8*)&Qs[(w * 16 + l15) * 136 + kd * 32 + quad * 8];

    float sums[4] = {0.f, 0.f, 0.f, 0.f};

    for (int m0 = 0; m0 < NN; m0 += 64) {
#pragma unroll
        for (int rep = 0; rep < 16; rep++) {
            int idx = rep * 256 + t;
            int row = idx >> 6, dp = idx & 63;
            *(uint*)&Qm2[row * 136 + dp * 2] = *(const uint*)&Qb[(m0 + row) * DD + dp * 2];
        }
        __syncthreads();
#pragma unroll
        for (int ct = 0; ct < 4; ct++) {
            floatx4 s = (floatx4)(0.0f);
#pragma unroll
            for (int kd = 0; kd < 4; kd++) {
                short8 bf = *(short8*)&Qm2[(ct * 16 + l15) * 136 + kd * 32 + quad * 8];
                s = __builtin_amdgcn_mfma_f32_16x16x32_bf16(afr[kd], bf, s, 0, 0, 0);
            }
#pragma unroll
            for (int r = 0; r < 4; r++)
                sums[r] += __expf(s[r] * RSCALE);
        }
        __syncthreads();
    }

#pragma unroll
    for (int r = 0; r < 4; r++) {
        float s = sums[r];
        s += __shfl_xor(s, 1);
        s += __shfl_xor(s, 2);
        s += __shfl_xor(s, 4);
        s += __shfl_xor(s, 8);
        sums[r] = s;
    }

    ushort* Vb = V + b * (NN * DD);
#pragma unroll
    for (int r = 0; r < 4; r++) {
        int n = n0 + w * 16 + quad * 4 + r;
        float inv = 1.0f / sums[r];
        short8 vv = *(short8*)&Vb[n * DD + l15 * 8];
        short8 o;
#pragma unroll
        for (int i = 0; i < 8; i++)
            o[i] = (short)f2bf(bf2f((ushort)vv[i]) * inv);
        *(short8*)&Vb[n * DD + l15 * 8] = o;
    }
}

__global__ __launch_bounds__(256) void k3_attn(
    const ushort* __restrict__ Q, const ushort* __restrict__ Vp,
    float* __restrict__ out)
{
    const int mtile = blockIdx.x;
    const int b = blockIdx.y;
    const int m0 = mtile * 64;
    const int t = threadIdx.x;
    const int lane = t & 63, w = t >> 6, l15 = lane & 15, quad = lane >> 4;

    __shared__ __attribute__((aligned(16))) ushort Qs[64 * 136];
    __shared__ __attribute__((aligned(16))) ushort Qn2[32 * 136];
    __shared__ __attribute__((aligned(16))) ushort Vs2[128 * 40];
    __shared__ __attribute__((aligned(16))) ushort Ps2[64 * 40];

    const ushort* Qb = Q + b * (NN * DD);
    const ushort* Vpb = Vp + b * (NN * DD);

#pragma unroll
    for (int rep = 0; rep < 16; rep++) {
        int idx = rep * 256 + t;
        int row = idx >> 6, dp = idx & 63;
        *(uint*)&Qs[row * 136 + dp * 2] = *(const uint*)&Qb[(m0 + row) * DD + dp * 2];
    }
    __syncthreads();

    short8 afr[4];
#pragma unroll
    for (int kd = 0; kd < 4; kd++)
        afr[kd] = *(short8*)&Qs[(w * 16 + l15) * 136 + kd * 32 + quad * 8];

    floatx4 acc[2][4];
#pragma unroll
    for (int s = 0; s < 2; s++)
#pragma unroll
        for (int mt = 0; mt < 4; mt++) acc[s][mt] = (floatx4)(0.0f);

    for (int n0c = 0; n0c < NN; n0c += 32) {
#pragma unroll
        for (int rep = 0; rep < 8; rep++) {
            int idx = rep * 256 + t;
            int row = idx >> 6, dp = idx & 63;
            *(uint*)&Qn2[row * 136 + dp * 2] = *(const uint*)&Qb[(n0c + row) * DD + dp * 2];
        }
#pragma unroll
        for (int rep = 0; rep < 8; rep++) {
            int idx = rep * 256 + t;
            int np = idx >> 7, d = idx & 127;
            uint v0 = Vpb[(n0c + np * 2) * DD + d];
            uint v1 = Vpb[(n0c + np * 2 + 1) * DD + d];
            *(uint*)&Vs2[d * 40 + np * 2] = v0 | (v1 << 16);
        }
        __syncthreads();

#pragma unroll
        for (int nt2 = 0; nt2 < 2; nt2++) {
            floatx4 s = (floatx4)(0.0f);
#pragma unroll
            for (int kd = 0; kd < 4; kd++) {
                short8 bf = *(short8*)&Qn2[(nt2 * 16 + l15) * 136 + kd * 32 + quad * 8];
                s = __builtin_amdgcn_mfma_f32_16x16x32_bf16(afr[kd], bf, s, 0, 0, 0);
            }
#pragma unroll
            for (int r = 0; r < 4; r++) {
                float p = __expf(s[r] * RSCALE);
                Ps2[(w * 16 + quad * 4 + r) * 40 + nt2 * 16 + l15] = f2bf(p);
            }
        }
        __syncthreads();

        short8 pb[4];
#pragma unroll
        for (int mt = 0; mt < 4; mt++)
            pb[mt] = *(short8*)&Ps2[(mt * 16 + l15) * 40 + quad * 8];
#pragma unroll
        for (int sub = 0; sub < 2; sub++) {
            short8 va = *(short8*)&Vs2[(w * 32 + sub * 16 + l15) * 40 + quad * 8];
#pragma unroll
            for (int mt = 0; mt < 4; mt++)
                acc[sub][mt] = __builtin_amdgcn_mfma_f32_16x16x32_bf16(va, pb[mt], acc[sub][mt], 0, 0, 0);
        }
        __syncthreads();
    }

    float* ob = out + (size_t)b * DD * NN;
#pragma unroll
    for (int sub = 0; sub < 2; sub++)
#pragma unroll
        for (int mt = 0; mt < 4; mt++)
#pragma unroll
            for (int r = 0; r < 4; r++) {
                int d = w * 32 + sub * 16 + quad * 4 + r;
                int m = m0 + mt * 16 + l15;
                ob[(size_t)d * NN + m] = acc[sub][mt][r];
            }
}

extern "C" void kernel_launch(void* const* d_in, const int* in_sizes, int n_in,
                              void* d_out, int out_size, void* d_ws, size_t ws_size,
                              hipStream_t stream) {
    const float* x   = (const float*)d_in[0];
    const float* wqk = (const float*)d_in[1];
    const float* wv  = (const float*)d_in[2];
    const float* bv  = (const float*)d_in[3];
    float* out = (float*)d_out;

    // ws: Q [0,4M) | VT [4M,8M) | Wbf @8M (256K) | lsum @8M+256K (64K)
    ushort* Q = (ushort*)d_ws;

    if (ws_size >= (size_t)33 * 1024 * 1024) {
        ushort* VT   = (ushort*)((char*)d_ws + (4u << 20));
        ushort* Wbf  = (ushort*)((char*)d_ws + (8u << 20));
        float*  lsum = (float*)((char*)d_ws + (8u << 20) + (256u << 10));

        k0_prep<<<512, 256, 0, stream>>>(wqk, wv, Wbf, lsum, out);
        k1_proj<<<dim3(64, 2, 8), 256, 0, stream>>>(x, Wbf, bv, Q, VT);

        // cooperative merged kl_sum + attention; fall back to 2-kernel path
        const ushort* Qc = Q; const ushort* VTc = VT;
        void* cargs[] = {(void*)&Qc, (void*)&VTc, (void*)&lsum, (void*)&out};
        hipError_t ce = hipLaunchCooperativeKernel(
            (const void*)k_coop, dim3(64, 2, 8), dim3(256, 1, 1), cargs, 0, stream);
        if (ce != hipSuccess) {
            kl_sum<<<dim3(136, 8), 256, 0, stream>>>(Q, lsum);
            k_fused_sep<<<dim3(64, 2, 8), 256, 0, stream>>>(Q, VT, lsum, out);
        }
    } else {
        ushort* V = (ushort*)((char*)d_ws + (4u << 20));
        k1_fb<<<dim3(64, 8), 256, 0, stream>>>(x, wqk, wv, bv, Q, V);
        k2_norm<<<dim3(32, 8), 256, 0, stream>>>(Q, V);
        k3_attn<<<dim3(32, 8), 256, 0, stream>>>(Q, V, out);
    }
}

// Round 9
// 149.260 us; speedup vs baseline: 2.3233x; 2.3233x over previous
//
#include <hip/hip_runtime.h>

typedef short short4v __attribute__((ext_vector_type(4)));
typedef short short8 __attribute__((ext_vector_type(8)));
typedef float floatx4 __attribute__((ext_vector_type(4)));
typedef unsigned int uint;
typedef unsigned short ushort;

#define CH 512
#define NN 2048
#define DD 128
#define RSCALE 0.08838834764831845f  // 1/sqrt(128)

__device__ __forceinline__ float bf2f(ushort u) {
    union { uint i; float f; } v; v.i = ((uint)u) << 16; return v.f;
}
__device__ __forceinline__ ushort f2bf(float f) {
    union { float f; uint u; } v; v.f = f;
    uint u = v.u;
    return (ushort)((u + 0x7fffu + ((u >> 16) & 1u)) >> 16);
}

// ---------------------------------------------------------------------------
// K0: weights -> bf16 AND zero lsum AND zero out (merged; one launch).
// ---------------------------------------------------------------------------
__global__ __launch_bounds__(256) void k0_prep(
    const float* __restrict__ wqk, const float* __restrict__ wv,
    ushort* __restrict__ Wbf, float* __restrict__ lsum,
    float* __restrict__ out)
{
    int gid = blockIdx.x * 256 + threadIdx.x;
    if (gid < 32768) {
        int base = gid * 4;
        const float* src = (base < 65536) ? (wqk + base) : (wv + base - 65536);
        float4 v = *(const float4*)src;
        short4v o;
        o[0] = (short)f2bf(v.x); o[1] = (short)f2bf(v.y);
        o[2] = (short)f2bf(v.z); o[3] = (short)f2bf(v.w);
        *(short4v*)&Wbf[base] = o;
    }
    if (gid < 16384) lsum[gid] = 0.0f;
    float4 z; z.x = 0.f; z.y = 0.f; z.z = 0.f; z.w = 0.f;
#pragma unroll
    for (int i = 0; i < 4; i++)
        *(float4*)&out[(size_t)(gid + i * 131072) * 4] = z;
}

// ---------------------------------------------------------------------------
// K1: projections, d-stack split across h; c-step 64 (8 iterations).
// Grid (64 nt, 2 h, 8 b) = 1024 blocks. LDS 33280 -> 4 blocks/CU.
// ---------------------------------------------------------------------------
__global__ __launch_bounds__(256) void k1_proj(
    const float* __restrict__ x,
    const ushort* __restrict__ Wbf,
    const float* __restrict__ bv,
    ushort* __restrict__ Q,
    ushort* __restrict__ VT)
{
    const int nt = blockIdx.x;   // 0..63
    const int h  = blockIdx.y;   // 0..1 (0: Q rows, 1: V rows)
    const int b  = blockIdx.z;   // 0..7
    const int n0 = nt * 32;
    const int t = threadIdx.x;
    const int lane = t & 63, w = t >> 6, l15 = lane & 15, quad = lane >> 4;

    __shared__ __attribute__((aligned(16))) ushort As[32 * 72];
    __shared__ __attribute__((aligned(16))) ushort Bs[128 * 72];
    __shared__ __attribute__((aligned(16))) ushort Vt[128 * 40];

    floatx4 acc[2][2];
#pragma unroll
    for (int i = 0; i < 2; i++)
#pragma unroll
        for (int j = 0; j < 2; j++) acc[i][j] = (floatx4)(0.0f);

    const float* xb = x + b * (CH * NN) + n0;
    const ushort* Wh = Wbf + h * 128 * CH;

    const int an = t & 31, ag = t >> 5;       // A-stage: n, c-chunk (0..7)

    for (int c0 = 0; c0 < CH; c0 += 64) {
        // stage A: [32 n][64 c], fp32 -> bf16, 8 elems/thread
        {
            short8 v;
#pragma unroll
            for (int i = 0; i < 8; i++)
                v[i] = (short)f2bf(xb[(c0 + ag * 8 + i) * NN + an]);
            *(short8*)&As[an * 72 + ag * 8] = v;
        }
        // stage B: [128 rows][64 c], 4 x b128/thread
#pragma unroll
        for (int rep = 0; rep < 4; rep++) {
            int idx = rep * 256 + t;
            int row = idx >> 3, g = idx & 7;
            *(short8*)&Bs[row * 72 + g * 8] = *(const short8*)&Wh[row * CH + c0 + g * 8];
        }
        __syncthreads();
#pragma unroll
        for (int kd = 0; kd < 2; kd++) {
            short8 a0 = *(short8*)&As[(l15) * 72 + kd * 32 + quad * 8];
            short8 a1 = *(short8*)&As[(16 + l15) * 72 + kd * 32 + quad * 8];
#pragma unroll
            for (int dt2 = 0; dt2 < 2; dt2++) {
                short8 bf = *(short8*)&Bs[(w * 32 + dt2 * 16 + l15) * 72 + kd * 32 + quad * 8];
                acc[0][dt2] = __builtin_amdgcn_mfma_f32_16x16x32_bf16(a0, bf, acc[0][dt2], 0, 0, 0);
                acc[1][dt2] = __builtin_amdgcn_mfma_f32_16x16x32_bf16(a1, bf, acc[1][dt2], 0, 0, 0);
            }
        }
        __syncthreads();
    }

    // epilogue
#pragma unroll
    for (int ns = 0; ns < 2; ns++)
#pragma unroll
        for (int dt2 = 0; dt2 < 2; dt2++) {
            int ds_ = w * 32 + dt2 * 16 + l15;  // 0..127
#pragma unroll
            for (int r = 0; r < 4; r++) {
                int nl = ns * 16 + quad * 4 + r;
                float val = acc[ns][dt2][r];
                if (h == 0) {
                    Q[b * (NN * DD) + (n0 + nl) * DD + ds_] = f2bf(val);
                } else {
                    Vt[ds_ * 40 + nl] = f2bf(val + bv[ds_]);
                }
            }
        }
    if (h == 1) {
        __syncthreads();
#pragma unroll
        for (int rep = 0; rep < 2; rep++) {
            int idx = rep * 256 + t;
            int dv = idx >> 2, seg = idx & 3;
            *(short8*)&VT[((size_t)b * DD + dv) * NN + n0 + seg * 8] =
                *(short8*)&Vt[dv * 40 + seg * 8];
        }
    }
}

// ---------------------------------------------------------------------------
// KP: S tiles -> P = e^S materialized to HBM (bf16) + lsum row-sums.
// Grid (256 tilepairs, 8 b). it=pid>>4, jt=pid&15 — ALL tiles (no symmetry
// shortcut; P written once per (i,j)). Staging/MFMA copied from proven kl_sum.
// After MFMA: Pt LDS bounce (overlays Qi/Qj; pad 138 -> conflict-free b16
// writes) then coalesced b128 global P writes. LDS 36864 -> 4 blocks/CU.
// ---------------------------------------------------------------------------
__global__ __launch_bounds__(256, 4) void k_p(
    const ushort* __restrict__ Q,   // [B][N][D] bf16
    ushort* __restrict__ P,         // [B][N][N] bf16 (e^S, unnormalized)
    float* __restrict__ lsum)       // [B][N] (pre-zeroed)
{
    const int pid = blockIdx.x;          // 0..255
    const int b = blockIdx.y;
    const int it = pid >> 4, jt = pid & 15;
    const int i0 = it * 128, j0 = jt * 128;
    const int t = threadIdx.x;
    const int lane = t & 63, w = t >> 6, l15 = lane & 15, quad = lane >> 4;
    const int wi = (w >> 1) * 64, wj = (w & 1) * 64;

    __shared__ __attribute__((aligned(16))) char smem[36864];
    ushort* Qi = (ushort*)smem;            // [128][72]
    ushort* Qj = (ushort*)(smem + 18432);  // [128][72]
    ushort* Pt = (ushort*)smem;            // [128][138] overlay after MFMA

    const ushort* Qb = Q + b * (NN * DD);

    floatx4 acc[4][4];
#pragma unroll
    for (int i = 0; i < 4; i++)
#pragma unroll
        for (int j = 0; j < 4; j++) acc[i][j] = (floatx4)(0.0f);

    for (int kh = 0; kh < 2; kh++) {
        if (kh) __syncthreads();
#pragma unroll
        for (int rep = 0; rep < 4; rep++) {
            int idx = rep * 256 + t;
            int row = idx >> 3, g = idx & 7;
            *(short8*)&Qi[row * 72 + g * 8] = *(const short8*)&Qb[(i0 + row) * DD + kh * 64 + g * 8];
            *(short8*)&Qj[row * 72 + g * 8] = *(const short8*)&Qb[(j0 + row) * DD + kh * 64 + g * 8];
        }
        __syncthreads();

#pragma unroll
        for (int kd = 0; kd < 2; kd++) {
            short8 afr[4], bfr[4];
#pragma unroll
            for (int nt = 0; nt < 4; nt++)
                afr[nt] = *(short8*)&Qi[(wi + nt * 16 + l15) * 72 + kd * 32 + quad * 8];
#pragma unroll
            for (int mt = 0; mt < 4; mt++)
                bfr[mt] = *(short8*)&Qj[(wj + mt * 16 + l15) * 72 + kd * 32 + quad * 8];
#pragma unroll
            for (int nt = 0; nt < 4; nt++)
#pragma unroll
                for (int mt = 0; mt < 4; mt++)
                    acc[nt][mt] = __builtin_amdgcn_mfma_f32_16x16x32_bf16(afr[nt], bfr[mt], acc[nt][mt], 0, 0, 0);
        }
    }

    __syncthreads();  // all waves done reading Qi/Qj before Pt overlay

    // exp + row-sum partials + LDS transpose-bounce
#pragma unroll
    for (int nt = 0; nt < 4; nt++) {
        float rs[4] = {0.f, 0.f, 0.f, 0.f};
#pragma unroll
        for (int mt = 0; mt < 4; mt++)
#pragma unroll
            for (int r = 0; r < 4; r++) {
                float p = __expf(acc[nt][mt][r] * RSCALE);
                rs[r] += p;
                Pt[(wi + nt * 16 + quad * 4 + r) * 138 + wj + mt * 16 + l15] = f2bf(p);
            }
#pragma unroll
        for (int r = 0; r < 4; r++) {
            float s = rs[r];
            s += __shfl_xor(s, 1);
            s += __shfl_xor(s, 2);
            s += __shfl_xor(s, 4);
            s += __shfl_xor(s, 8);
            if (l15 == 0)
                atomicAdd(&lsum[b * NN + i0 + wi + nt * 16 + quad * 4 + r], s);
        }
    }
    __syncthreads();

    // coalesced P write: 128 rows x 256 B
    ushort* Pb = P + (size_t)b * NN * NN;
#pragma unroll
    for (int rep = 0; rep < 8; rep++) {
        int idx = rep * 256 + t;
        int row = idx >> 4, g = idx & 15;
        *(short8*)&Pb[(size_t)(i0 + row) * NN + j0 + g * 8] =
            *(short8*)&Pt[row * 138 + g * 8];
    }
}

// ---------------------------------------------------------------------------
// KVS: Vsc[b][d][n] = VT[b][d][n] / lsum[b][n]  (2.1M elems, 8/thread)
// ---------------------------------------------------------------------------
__global__ __launch_bounds__(256) void k_vscale(
    const ushort* __restrict__ VT, const float* __restrict__ lsum,
    ushort* __restrict__ Vsc)
{
    int gid = blockIdx.x * 256 + threadIdx.x;  // 1024 blocks
    size_t idx = (size_t)gid * 8;
    int b = (int)(idx >> 18);        // DD*NN = 262144
    int n = (int)(idx & (NN - 1));
    short8 v = *(const short8*)&VT[idx];
    float4 l0 = *(const float4*)&lsum[b * NN + n];
    float4 l1 = *(const float4*)&lsum[b * NN + n + 4];
    short8 o;
    o[0] = (short)f2bf(bf2f((ushort)v[0]) / l0.x);
    o[1] = (short)f2bf(bf2f((ushort)v[1]) / l0.y);
    o[2] = (short)f2bf(bf2f((ushort)v[2]) / l0.z);
    o[3] = (short)f2bf(bf2f((ushort)v[3]) / l0.w);
    o[4] = (short)f2bf(bf2f((ushort)v[4]) / l1.x);
    o[5] = (short)f2bf(bf2f((ushort)v[5]) / l1.y);
    o[6] = (short)f2bf(bf2f((ushort)v[6]) / l1.z);
    o[7] = (short)f2bf(bf2f((ushort)v[7]) / l1.w);
    *(short8*)&Vsc[idx] = o;
}

// ---------------------------------------------------------------------------
// KPV: out[b][d][m] = sum_n Vsc[d][n] * P[m][n]  (P symmetric: = P[n][m]).
// k_fused's exact loop MINUS the S/exp/Ps phase: per iter just stage + MFMA,
// 2 barriers. Grid (64 mt, 2 h, 8 b) = 1024 -> 4+ blocks/CU. T14 prefetch.
// 2-contrib fp32 atomic epilogue (out pre-zeroed in k0). LDS 23040.
// ---------------------------------------------------------------------------
__global__ __launch_bounds__(256, 4) void k_pv(
    const ushort* __restrict__ Vsc, // [B][D][N] bf16 (V/l)
    const ushort* __restrict__ P,   // [B][N][N] bf16
    float* __restrict__ out)        // [B][D][N] fp32 (pre-zeroed)
{
    const int mt = blockIdx.x;  // 0..63
    const int h  = blockIdx.y;  // 0..1
    const int b  = blockIdx.z;
    const int m0 = mt * 32;
    const int t = threadIdx.x;
    const int lane = t & 63, w = t >> 6, l15 = lane & 15, quad = lane >> 4;

    __shared__ __attribute__((aligned(16))) ushort Vs[128 * 72];
    __shared__ __attribute__((aligned(16))) ushort Pp[32 * 72];

    const ushort* Vb = Vsc + (size_t)b * DD * NN;
    const ushort* Pb = P + (size_t)b * NN * NN;

    floatx4 acc[2][2];
#pragma unroll
    for (int i = 0; i < 2; i++)
#pragma unroll
        for (int j = 0; j < 2; j++) acc[i][j] = (floatx4)(0.0f);

    const int vsd = t >> 3, vsg = t & 7;   // Vs: d sub (32/rep), 16B chunk
    const int psr = t >> 3, psg = t & 7;   // Pp: m row (0..31), 16B chunk

    short8 vr[4], pr;  // in-flight next tile (T14)

#define LOADR(NC)                                                              \
    do {                                                                       \
        _Pragma("unroll")                                                      \
        for (int rep = 0; rep < 4; rep++)                                      \
            vr[rep] = *(const short8*)&Vb[(size_t)(rep * 32 + vsd) * NN + (NC) + vsg * 8]; \
        pr = *(const short8*)&Pb[(size_t)(m0 + psr) * NN + (NC) + psg * 8];    \
    } while (0)

    const int nbeg = h * (NN / 2), nend = nbeg + (NN / 2);

    LOADR(nbeg);  // prologue fetch

    for (int n0c = nbeg; n0c < nend; n0c += 64) {
        __syncthreads();  // prior iter's reads complete
#pragma unroll
        for (int rep = 0; rep < 4; rep++)
            *(short8*)&Vs[(rep * 32 + vsd) * 72 + vsg * 8] = vr[rep];
        *(short8*)&Pp[psr * 72 + psg * 8] = pr;
        __syncthreads();  // tile visible

        if (n0c + 64 < nend) LOADR(n0c + 64);

        // PV: wave w owns d-band w*32; m full 32
#pragma unroll
        for (int kn = 0; kn < 2; kn++) {
            short8 va0 = *(short8*)&Vs[(w * 32 + l15) * 72 + kn * 32 + quad * 8];
            short8 va1 = *(short8*)&Vs[(w * 32 + 16 + l15) * 72 + kn * 32 + quad * 8];
#pragma unroll
            for (int mf = 0; mf < 2; mf++) {
                short8 pb = *(short8*)&Pp[(mf * 16 + l15) * 72 + kn * 32 + quad * 8];
                acc[0][mf] = __builtin_amdgcn_mfma_f32_16x16x32_bf16(va0, pb, acc[0][mf], 0, 0, 0);
                acc[1][mf] = __builtin_amdgcn_mfma_f32_16x16x32_bf16(va1, pb, acc[1][mf], 0, 0, 0);
            }
        }
    }
#undef LOADR

    // epilogue: atomic accumulate into out (2 contributions/element)
    float* ob = out + (size_t)b * DD * NN;
#pragma unroll
    for (int dsub = 0; dsub < 2; dsub++)
#pragma unroll
        for (int mf = 0; mf < 2; mf++)
#pragma unroll
            for (int r = 0; r < 4; r++) {
                int d = w * 32 + dsub * 16 + quad * 4 + r;
                atomicAdd(&ob[(size_t)d * NN + m0 + mf * 16 + l15], acc[dsub][mf][r]);
            }
}

// ---------------------------------------------------------------------------
// KL: l_n row sums (MID-TIER path). Proven round-3 version.
// ---------------------------------------------------------------------------
__global__ __launch_bounds__(256, 4) void kl_sum(
    const ushort* __restrict__ Q,   // [B][N][D] bf16
    float* __restrict__ lsum)       // [B][N]
{
    int pid = blockIdx.x;  // 0..135
    const int b = blockIdx.y;
    int it = 0;
    while (pid >= (16 - it)) { pid -= (16 - it); it++; }
    const int jt = it + pid;
    const int i0 = it * 128, j0 = jt * 128;
    const int t = threadIdx.x;
    const int lane = t & 63, w = t >> 6, l15 = lane & 15, quad = lane >> 4;
    const int wi = (w >> 1) * 64, wj = (w & 1) * 64;

    __shared__ __attribute__((aligned(16))) ushort Qi[128 * 72];
    __shared__ __attribute__((aligned(16))) ushort Qj[128 * 72];

    const ushort* Qb = Q + b * (NN * DD);

    floatx4 acc[4][4];
#pragma unroll
    for (int i = 0; i < 4; i++)
#pragma unroll
        for (int j = 0; j < 4; j++) acc[i][j] = (floatx4)(0.0f);

    for (int kh = 0; kh < 2; kh++) {
        if (kh) __syncthreads();
#pragma unroll
        for (int rep = 0; rep < 4; rep++) {
            int idx = rep * 256 + t;
            int row = idx >> 3, g = idx & 7;
            *(short8*)&Qi[row * 72 + g * 8] = *(const short8*)&Qb[(i0 + row) * DD + kh * 64 + g * 8];
            *(short8*)&Qj[row * 72 + g * 8] = *(const short8*)&Qb[(j0 + row) * DD + kh * 64 + g * 8];
        }
        __syncthreads();

#pragma unroll
        for (int kd = 0; kd < 2; kd++) {
            short8 afr[4], bfr[4];
#pragma unroll
            for (int nt = 0; nt < 4; nt++)
                afr[nt] = *(short8*)&Qi[(wi + nt * 16 + l15) * 72 + kd * 32 + quad * 8];
#pragma unroll
            for (int mt = 0; mt < 4; mt++)
                bfr[mt] = *(short8*)&Qj[(wj + mt * 16 + l15) * 72 + kd * 32 + quad * 8];
#pragma unroll
            for (int nt = 0; nt < 4; nt++)
#pragma unroll
                for (int mt = 0; mt < 4; mt++)
                    acc[nt][mt] = __builtin_amdgcn_mfma_f32_16x16x32_bf16(afr[nt], bfr[mt], acc[nt][mt], 0, 0, 0);
        }
    }

    float cs[4] = {0.f, 0.f, 0.f, 0.f};
#pragma unroll
    for (int nt = 0; nt < 4; nt++) {
        float rs[4] = {0.f, 0.f, 0.f, 0.f};
#pragma unroll
        for (int mt = 0; mt < 4; mt++)
#pragma unroll
            for (int r = 0; r < 4; r++) {
                float p = __expf(acc[nt][mt][r] * RSCALE);
                rs[r] += p;
                cs[mt] += p;
            }
#pragma unroll
        for (int r = 0; r < 4; r++) {
            float s = rs[r];
            s += __shfl_xor(s, 1);
            s += __shfl_xor(s, 2);
            s += __shfl_xor(s, 4);
            s += __shfl_xor(s, 8);
            if (l15 == 0)
                atomicAdd(&lsum[b * NN + i0 + wi + nt * 16 + quad * 4 + r], s);
        }
    }
    if (it != jt) {
#pragma unroll
        for (int mt = 0; mt < 4; mt++) {
            float s = cs[mt];
            s += __shfl_xor(s, 16);
            s += __shfl_xor(s, 32);
            if (lane < 16)
                atomicAdd(&lsum[b * NN + j0 + wj + mt * 16 + l15], s);
        }
    }
}

// ---------------------------------------------------------------------------
// K3 (MID-TIER): round-3 proven fused attention, h=2, 2-contrib atomics.
// ---------------------------------------------------------------------------
__global__ __launch_bounds__(256, 4) void k_fused_sep(
    const ushort* __restrict__ Q,
    const ushort* __restrict__ VT,
    const float* __restrict__ lsum,
    float* __restrict__ out)
{
    const int mt = blockIdx.x;  // 0..63
    const int h  = blockIdx.y;  // 0..1
    const int b  = blockIdx.z;
    const int m0 = mt * 32;
    const int t = threadIdx.x;
    const int lane = t & 63, w = t >> 6, l15 = lane & 15, quad = lane >> 4;

    __shared__ __attribute__((aligned(16))) ushort Qn[64 * 136];
    __shared__ __attribute__((aligned(16))) ushort Vs[128 * 72];
    __shared__ __attribute__((aligned(16))) ushort Ps[32 * 68];

    const ushort* Qb = Q + b * (NN * DD);
    const ushort* VTb = VT + (size_t)b * DD * NN;
    const float* lb = lsum + b * NN;

#pragma unroll
    for (int rep = 0; rep < 2; rep++) {
        int idx = rep * 256 + t;
        int row = idx >> 4, g = idx & 15;
        *(short8*)&Qn[row * 136 + g * 8] = *(const short8*)&Qb[(m0 + row) * DD + g * 8];
    }
    __syncthreads();

    short8 qm[2][4];
#pragma unroll
    for (int ms = 0; ms < 2; ms++)
#pragma unroll
        for (int kd = 0; kd < 4; kd++)
            qm[ms][kd] = *(short8*)&Qn[(ms * 16 + l15) * 136 + kd * 32 + quad * 8];

    floatx4 acc[2][2];
#pragma unroll
    for (int i = 0; i < 2; i++)
#pragma unroll
        for (int j = 0; j < 2; j++) acc[i][j] = (floatx4)(0.0f);

    const int qsr = t >> 4, qsg = t & 15;
    const int vsd = t >> 3, vsg = t & 7;

    short8 qr[4], vr[4];

#define LOADR(NC)                                                              \
    do {                                                                       \
        _Pragma("unroll")                                                      \
        for (int rep = 0; rep < 4; rep++)                                      \
            qr[rep] = *(const short8*)&Qb[((NC) + rep * 16 + qsr) * DD + qsg * 8]; \
        _Pragma("unroll")                                                      \
        for (int rep = 0; rep < 4; rep++)                                      \
            vr[rep] = *(const short8*)&VTb[(size_t)(rep * 32 + vsd) * NN + (NC) + vsg * 8]; \
    } while (0)

    const int nbeg = h * (NN / 2), nend = nbeg + (NN / 2);

    LOADR(nbeg);

    for (int n0c = nbeg; n0c < nend; n0c += 64) {
        float lw = lb[n0c + w * 16 + l15];
        __syncthreads();
#pragma unroll
        for (int rep = 0; rep < 4; rep++)
            *(short8*)&Qn[(rep * 16 + qsr) * 136 + qsg * 8] = qr[rep];
#pragma unroll
        for (int rep = 0; rep < 4; rep++)
            *(short8*)&Vs[(rep * 32 + vsd) * 72 + vsg * 8] = vr[rep];
        __syncthreads();

        if (n0c + 64 < nend) LOADR(n0c + 64);

        {
            float linv = 1.0f / lw;
            short8 bq[4];
#pragma unroll
            for (int kd = 0; kd < 4; kd++)
                bq[kd] = *(short8*)&Qn[(w * 16 + l15) * 136 + kd * 32 + quad * 8];
#pragma unroll
            for (int ms = 0; ms < 2; ms++) {
                floatx4 s = (floatx4)(0.0f);
#pragma unroll
                for (int kd = 0; kd < 4; kd++)
                    s = __builtin_amdgcn_mfma_f32_16x16x32_bf16(qm[ms][kd], bq[kd], s, 0, 0, 0);
#pragma unroll
                for (int r = 0; r < 4; r++) {
                    float p = __expf(s[r] * RSCALE) * linv;
                    Ps[(ms * 16 + quad * 4 + r) * 68 + w * 16 + l15] = f2bf(p);
                }
            }
        }
        __syncthreads();

#pragma unroll
        for (int kn = 0; kn < 2; kn++) {
            short8 va0 = *(short8*)&Vs[(w * 32 + l15) * 72 + kn * 32 + quad * 8];
            short8 va1 = *(short8*)&Vs[(w * 32 + 16 + l15) * 72 + kn * 32 + quad * 8];
#pragma unroll
            for (int mf = 0; mf < 2; mf++) {
                short8 pb = *(short8*)&Ps[(mf * 16 + l15) * 68 + kn * 32 + quad * 8];
                acc[0][mf] = __builtin_amdgcn_mfma_f32_16x16x32_bf16(va0, pb, acc[0][mf], 0, 0, 0);
                acc[1][mf] = __builtin_amdgcn_mfma_f32_16x16x32_bf16(va1, pb, acc[1][mf], 0, 0, 0);
            }
        }
    }
#undef LOADR

    float* ob = out + (size_t)b * DD * NN;
#pragma unroll
    for (int dsub = 0; dsub < 2; dsub++)
#pragma unroll
        for (int mf = 0; mf < 2; mf++)
#pragma unroll
            for (int r = 0; r < 4; r++) {
                int d = w * 32 + dsub * 16 + quad * 4 + r;
                atomicAdd(&ob[(size_t)d * NN + m0 + mf * 16 + l15], acc[dsub][mf][r]);
            }
}

// ---------------------------------------------------------------------------
// Fallback path (small ws) — proven kernels
// ---------------------------------------------------------------------------
__global__ __launch_bounds__(256) void k1_fb(
    const float* __restrict__ x, const float* __restrict__ wqk,
    const float* __restrict__ wv, const float* __restrict__ bv,
    ushort* __restrict__ Q, ushort* __restrict__ V)
{
    const int nt = blockIdx.x;
    const int b  = blockIdx.y;
    const int n0 = nt * 32;
    const int t = threadIdx.x;
    const int lane = t & 63, w = t >> 6, l15 = lane & 15, quad = lane >> 4;

    __shared__ __attribute__((aligned(16))) ushort As[32 * 40];
    __shared__ __attribute__((aligned(16))) ushort Bs[256 * 40];

    floatx4 acc[2][4];
#pragma unroll
    for (int i = 0; i < 2; i++)
#pragma unroll
        for (int j = 0; j < 4; j++) acc[i][j] = (floatx4)(0.0f);

    const float* xb = x + b * (CH * NN) + n0;

    for (int c0 = 0; c0 < CH; c0 += 32) {
        {
            int n = t & 31, g = t >> 5;
            short4v v;
#pragma unroll
            for (int i = 0; i < 4; i++)
                v[i] = (short)f2bf(xb[(c0 + g * 4 + i) * NN + n]);
            *(short4v*)&As[n * 40 + g * 4] = v;
        }
#pragma unroll
        for (int rep = 0; rep < 16; rep++) {
            int idx = rep * 256 + t;
            int row = idx >> 4, cp = idx & 15;
            const float* wf = (row < 128) ? (wqk + row * CH) : (wv + (row - 128) * CH);
            uint pack = (uint)f2bf(wf[c0 + cp * 2]) | ((uint)f2bf(wf[c0 + cp * 2 + 1]) << 16);
            *(uint*)&Bs[row * 40 + cp * 2] = pack;
        }
        __syncthreads();
        short8 a0 = *(short8*)&As[(l15) * 40 + quad * 8];
        short8 a1 = *(short8*)&As[(16 + l15) * 40 + quad * 8];
#pragma unroll
        for (int dt2 = 0; dt2 < 4; dt2++) {
            short8 bf = *(short8*)&Bs[(w * 64 + dt2 * 16 + l15) * 40 + quad * 8];
            acc[0][dt2] = __builtin_amdgcn_mfma_f32_16x16x32_bf16(a0, bf, acc[0][dt2], 0, 0, 0);
            acc[1][dt2] = __builtin_amdgcn_mfma_f32_16x16x32_bf16(a1, bf, acc[1][dt2], 0, 0, 0);
        }
        __syncthreads();
    }
#pragma unroll
    for (int ns = 0; ns < 2; ns++)
#pragma unroll
        for (int dt2 = 0; dt2 < 4; dt2++) {
            int ds_ = w * 64 + dt2 * 16 + l15;
#pragma unroll
            for (int r = 0; r < 4; r++) {
                int n = n0 + ns * 16 + quad * 4 + r;
                float val = acc[ns][dt2][r];
                if (ds_ < 128) {
                    Q[b * (NN * DD) + n * DD + ds_] = f2bf(val);
                } else {
                    int dv = ds_ - 128;
                    V[b * (NN * DD) + n * DD + dv] = f2bf(val + bv[dv]);
                }
            }
        }
}

__global__ __launch_bounds__(256) void k2_norm(
    const ushort* __restrict__ Q, ushort* __restrict__ V)
{
    const int ntile = blockIdx.x;
    const int b = blockIdx.y;
    const int n0 = ntile * 64;
    const int t = threadIdx.x;
    const int lane = t & 63, w = t >> 6, l15 = lane & 15, quad = lane >> 4;

    __shared__ __attribute__((aligned(16))) ushort Qs[64 * 136];
    __shared__ __attribute__((aligned(16))) ushort Qm2[64 * 136];

    const ushort* Qb = Q + b * (NN * DD);

#pragma unroll
    for (int rep = 0; rep < 16; rep++) {
        int idx = rep * 256 + t;
        int row = idx >> 6, dp = idx & 63;
        *(uint*)&Qs[row * 136 + dp * 2] = *(const uint*)&Qb[(n0 + row) * DD + dp * 2];
    }
    __syncthreads();

    short8 afr[4];
#pragma unroll
    for (int kd = 0; kd < 4; kd++)
        afr[kd] = *(short8*)&Qs[(w * 16 + l15) * 136 + kd * 32 + quad * 8];

    float sums[4] = {0.f, 0.f, 0.f, 0.f};

    for (int m0 = 0; m0 < NN; m0 += 64) {
#pragma unroll
        for (int rep = 0; rep < 16; rep++) {
            int idx = rep * 256 + t;
            int row = idx >> 6, dp = idx & 63;
            *(uint*)&Qm2[row * 136 + dp * 2] = *(const uint*)&Qb[(m0 + row) * DD + dp * 2];
        }
        __syncthreads();
#pragma unroll
        for (int ct = 0; ct < 4; ct++) {
            floatx4 s = (floatx4)(0.0f);
#pragma unroll
            for (int kd = 0; kd < 4; kd++) {
                short8 bf = *(short8*)&Qm2[(ct * 16 + l15) * 136 + kd * 32 + quad * 8];
                s = __builtin_amdgcn_mfma_f32_16x16x32_bf16(afr[kd], bf, s, 0, 0, 0);
            }
#pragma unroll
            for (int r = 0; r < 4; r++)
                sums[r] += __expf(s[r] * RSCALE);
        }
        __syncthreads();
    }

#pragma unroll
    for (int r = 0; r < 4; r++) {
        float s = sums[r];
        s += __shfl_xor(s, 1);
        s += __shfl_xor(s, 2);
        s += __shfl_xor(s, 4);
        s += __shfl_xor(s, 8);
        sums[r] = s;
    }

    ushort* Vb = V + b * (NN * DD);
#pragma unroll
    for (int r = 0; r < 4; r++) {
        int n = n0 + w * 16 + quad * 4 + r;
        float inv = 1.0f / sums[r];
        short8 vv = *(short8*)&Vb[n * DD + l15 * 8];
        short8 o;
#pragma unroll
        for (int i = 0; i < 8; i++)
            o[i] = (short)f2bf(bf2f((ushort)vv[i]) * inv);
        *(short8*)&Vb[n * DD + l15 * 8] = o;
    }
}

__global__ __launch_bounds__(256) void k3_attn(
    const ushort* __restrict__ Q, const ushort* __restrict__ Vp,
    float* __restrict__ out)
{
    const int mtile = blockIdx.x;
    const int b = blockIdx.y;
    const int m0 = mtile * 64;
    const int t = threadIdx.x;
    const int lane = t & 63, w = t >> 6, l15 = lane & 15, quad = lane >> 4;

    __shared__ __attribute__((aligned(16))) ushort Qs[64 * 136];
    __shared__ __attribute__((aligned(16))) ushort Qn2[32 * 136];
    __shared__ __attribute__((aligned(16))) ushort Vs2[128 * 40];
    __shared__ __attribute__((aligned(16))) ushort Ps2[64 * 40];

    const ushort* Qb = Q + b * (NN * DD);
    const ushort* Vpb = Vp + b * (NN * DD);

#pragma unroll
    for (int rep = 0; rep < 16; rep++) {
        int idx = rep * 256 + t;
        int row = idx >> 6, dp = idx & 63;
        *(uint*)&Qs[row * 136 + dp * 2] = *(const uint*)&Qb[(m0 + row) * DD + dp * 2];
    }
    __syncthreads();

    short8 afr[4];
#pragma unroll
    for (int kd = 0; kd < 4; kd++)
        afr[kd] = *(short8*)&Qs[(w * 16 + l15) * 136 + kd * 32 + quad * 8];

    floatx4 acc[2][4];
#pragma unroll
    for (int s = 0; s < 2; s++)
#pragma unroll
        for (int mt = 0; mt < 4; mt++) acc[s][mt] = (floatx4)(0.0f);

    for (int n0c = 0; n0c < NN; n0c += 32) {
#pragma unroll
        for (int rep = 0; rep < 8; rep++) {
            int idx = rep * 256 + t;
            int row = idx >> 6, dp = idx & 63;
            *(uint*)&Qn2[row * 136 + dp * 2] = *(const uint*)&Qb[(n0c + row) * DD + dp * 2];
        }
#pragma unroll
        for (int rep = 0; rep < 8; rep++) {
            int idx = rep * 256 + t;
            int np = idx >> 7, d = idx & 127;
            uint v0 = Vpb[(n0c + np * 2) * DD + d];
            uint v1 = Vpb[(n0c + np * 2 + 1) * DD + d];
            *(uint*)&Vs2[d * 40 + np * 2] = v0 | (v1 << 16);
        }
        __syncthreads();

#pragma unroll
        for (int nt2 = 0; nt2 < 2; nt2++) {
            floatx4 s = (floatx4)(0.0f);
#pragma unroll
            for (int kd = 0; kd < 4; kd++) {
                short8 bf = *(short8*)&Qn2[(nt2 * 16 + l15) * 136 + kd * 32 + quad * 8];
                s = __builtin_amdgcn_mfma_f32_16x16x32_bf16(afr[kd], bf, s, 0, 0, 0);
            }
#pragma unroll
            for (int r = 0; r < 4; r++) {
                float p = __expf(s[r] * RSCALE);
                Ps2[(w * 16 + quad * 4 + r) * 40 + nt2 * 16 + l15] = f2bf(p);
            }
        }
        __syncthreads();

        short8 pb[4];
#pragma unroll
        for (int mt = 0; mt < 4; mt++)
            pb[mt] = *(short8*)&Ps2[(mt * 16 + l15) * 40 + quad * 8];
#pragma unroll
        for (int sub = 0; sub < 2; sub++) {
            short8 va = *(short8*)&Vs2[(w * 32 + sub * 16 + l15) * 40 + quad * 8];
#pragma unroll
            for (int mt = 0; mt < 4; mt++)
                acc[sub][mt] = __builtin_amdgcn_mfma_f32_16x16x32_bf16(va, pb[mt], acc[sub][mt], 0, 0, 0);
        }
        __syncthreads();
    }

    float* ob = out + (size_t)b * DD * NN;
#pragma unroll
    for (int sub = 0; sub < 2; sub++)
#pragma unroll
        for (int mt = 0; mt < 4; mt++)
#pragma unroll
            for (int r = 0; r < 4; r++) {
                int d = w * 32 + sub * 16 + quad * 4 + r;
                int m = m0 + mt * 16 + l15;
                ob[(size_t)d * NN + m] = acc[sub][mt][r];
            }
}

extern "C" void kernel_launch(void* const* d_in, const int* in_sizes, int n_in,
                              void* d_out, int out_size, void* d_ws, size_t ws_size,
                              hipStream_t stream) {
    const float* x   = (const float*)d_in[0];
    const float* wqk = (const float*)d_in[1];
    const float* wv  = (const float*)d_in[2];
    const float* bv  = (const float*)d_in[3];
    float* out = (float*)d_out;

    // ws: Q@0 (4M) | VT@4M (4M) | Wbf@8M (256K) | lsum@8M+256K (64K)
    //   | Vsc@9M (4M) | P@16M (64M)  -> 80 MiB total (big tier)
    ushort* Q = (ushort*)d_ws;

    if (ws_size >= ((size_t)80 << 20)) {
        ushort* VT   = (ushort*)((char*)d_ws + (4u << 20));
        ushort* Wbf  = (ushort*)((char*)d_ws + (8u << 20));
        float*  lsum = (float*)((char*)d_ws + (8u << 20) + (256u << 10));
        ushort* Vsc  = (ushort*)((char*)d_ws + (9u << 20));
        ushort* P    = (ushort*)((char*)d_ws + (16u << 20));

        k0_prep<<<512, 256, 0, stream>>>(wqk, wv, Wbf, lsum, out);
        k1_proj<<<dim3(64, 2, 8), 256, 0, stream>>>(x, Wbf, bv, Q, VT);
        k_p<<<dim3(256, 8), 256, 0, stream>>>(Q, P, lsum);
        k_vscale<<<1024, 256, 0, stream>>>(VT, lsum, Vsc);
        k_pv<<<dim3(64, 2, 8), 256, 0, stream>>>(Vsc, P, out);
    } else if (ws_size >= (size_t)33 * 1024 * 1024) {
        ushort* VT   = (ushort*)((char*)d_ws + (4u << 20));
        ushort* Wbf  = (ushort*)((char*)d_ws + (8u << 20));
        float*  lsum = (float*)((char*)d_ws + (8u << 20) + (256u << 10));

        k0_prep<<<512, 256, 0, stream>>>(wqk, wv, Wbf, lsum, out);
        k1_proj<<<dim3(64, 2, 8), 256, 0, stream>>>(x, Wbf, bv, Q, VT);
        kl_sum<<<dim3(136, 8), 256, 0, stream>>>(Q, lsum);
        k_fused_sep<<<dim3(64, 2, 8), 256, 0, stream>>>(Q, VT, lsum, out);
    } else {
        ushort* V = (ushort*)((char*)d_ws + (4u << 20));
        k1_fb<<<dim3(64, 8), 256, 0, stream>>>(x, wqk, wv, bv, Q, V);
        k2_norm<<<dim3(32, 8), 256, 0, stream>>>(Q, V);
        k3_attn<<<dim3(32, 8), 256, 0, stream>>>(Q, V, out);
    }
}